// Round 1
// baseline (258.148 us; speedup 1.0000x reference)
//
#include <hip/hip_runtime.h>
#include <cstdint>
#include <cstddef>

#define BB   32
#define NN   1024
#define FIN  128
#define FOUT 128

typedef __attribute__((ext_vector_type(8))) short bf16x8;
typedef __attribute__((ext_vector_type(4))) float f32x4;

__device__ __forceinline__ unsigned int f2bf(float f) {
    union { float f; unsigned int u; } v; v.f = f;
    unsigned int u = v.u;
    return (u + 0x7FFFu + ((u >> 16) & 1u)) >> 16;   // RNE fp32 -> bf16
}
__device__ __forceinline__ unsigned int pack2(float a, float b) {
    return f2bf(a) | (f2bf(b) << 16);
}

// ---------------------------------------------------------------------------
// Kernel 1: Yt[b][o][m] = sum_f node[b][m][f] * W[o][f]  (bf16, [B][FOUT][NN])
// (unchanged — control; ~24 MB traffic, not the dominant cost)
// ---------------------------------------------------------------------------
__global__ __launch_bounds__(256) void y_kernel(const float* __restrict__ node,
                                                const float* __restrict__ W,
                                                unsigned short* __restrict__ Yt) {
    __shared__ unsigned short Wlds[128 * 136];
    __shared__ unsigned short Nlds[64 * 136];

    const int tid = threadIdx.x;
    const int bid = blockIdx.x;
    const int b   = bid >> 4;
    const int m0  = (bid & 15) * 64;

    #pragma unroll
    for (int i = 0; i < 16; ++i) {
        const int idx = i * 256 + tid;
        const int row = idx >> 5;
        const int c   = (idx & 31) * 4;
        float4 v = ((const float4*)W)[idx];
        uint2 p; p.x = pack2(v.x, v.y); p.y = pack2(v.z, v.w);
        *(uint2*)&Wlds[row * 136 + c] = p;
    }
    {
        const float* base = node + ((size_t)b * NN + m0) * FIN;
        #pragma unroll
        for (int i = 0; i < 8; ++i) {
            const int idx = i * 256 + tid;
            const int row = idx >> 5;
            const int c   = (idx & 31) * 4;
            float4 v = *(const float4*)(base + row * FIN + c);
            uint2 p; p.x = pack2(v.x, v.y); p.y = pack2(v.z, v.w);
            *(uint2*)&Nlds[row * 136 + c] = p;
        }
    }
    __syncthreads();

    const int w = tid >> 6, lane = tid & 63;
    const int wo = w * 32;
    const int lcol = lane & 15, lk = (lane >> 4) * 8;

    f32x4 acc[2][4] = {};
    #pragma unroll
    for (int kc = 0; kc < 4; ++kc) {
        const int kof = kc * 32 + lk;
        bf16x8 a[2], bb[4];
        #pragma unroll
        for (int mi = 0; mi < 2; ++mi)
            a[mi] = *(const bf16x8*)&Wlds[(wo + mi*16 + lcol) * 136 + kof];
        #pragma unroll
        for (int ni = 0; ni < 4; ++ni)
            bb[ni] = *(const bf16x8*)&Nlds[(ni*16 + lcol) * 136 + kof];
        #pragma unroll
        for (int mi = 0; mi < 2; ++mi)
            #pragma unroll
            for (int ni = 0; ni < 4; ++ni)
                acc[mi][ni] = __builtin_amdgcn_mfma_f32_16x16x32_bf16(
                    a[mi], bb[ni], acc[mi][ni], 0, 0, 0);
    }
    __syncthreads();

    unsigned short* Ylds = Wlds;
    const int rq = (lane >> 4) * 4;
    #pragma unroll
    for (int mi = 0; mi < 2; ++mi)
        #pragma unroll
        for (int ni = 0; ni < 4; ++ni)
            #pragma unroll
            for (int r = 0; r < 4; ++r) {
                const int o = wo + mi * 16 + rq + r;
                const int m = ni * 16 + lcol;
                Ylds[o * 72 + m] = (unsigned short)f2bf(acc[mi][ni][r]);
            }
    __syncthreads();

    {
        const int oq = tid >> 3, c = (tid & 7) * 8;
        #pragma unroll
        for (int j = 0; j < 4; ++j) {
            const int o = oq + 32 * j;
            uint4 v = *(const uint4*)&Ylds[o * 72 + c];
            *(uint4*)(Yt + ((size_t)b * FOUT + o) * NN + m0 + c) = v;
        }
    }
}

// ---------------------------------------------------------------------------
// Kernel 2 v3: zero-LDS, zero-barrier streaming MFMA.
//   out = leaky( (adj @ Yt^T) / rowsum(adj) + bias )
// adj has zero reuse -> stream fp32 straight to registers, pack to bf16
// in-flight (fused with rowsum). Yt is 256 KB/batch -> L2-resident, read
// 16B/lane directly as the B-fragment (Common-mistake #7: don't stage
// cache-fit data). Fragment k-indices (kc*32 + q*8) are byte-identical to
// the verified LDS path, so numerics are unchanged.
// grid 512 = 32 b x 16 row-tiles(64); block 256 = 4 waves, each wave owns
// 16 rows x 128 cols (acc[8], adj read exactly once by exactly one lane).
// XCD-contiguous bid swizzle (512 %% 8 == 0 -> bijective) keeps each XCD's
// Yt working set at 4 batches = 1 MB < 4 MiB L2 (default round-robin would
// put all 32 batches = 8 MB on every XCD and thrash).
// Rowsum: lane (q,lcol) holds disjoint k-slices of row lcol -> xor16/xor32
// reduce + __shfl broadcast; no LDS, no barriers anywhere.
// ---------------------------------------------------------------------------
__global__ __launch_bounds__(256, 2) void gcn_kernel(const float* __restrict__ adj,
                                                     const unsigned short* __restrict__ Yt,
                                                     const float* __restrict__ bias,
                                                     float* __restrict__ out) {
    const int tid  = threadIdx.x;
    const int lane = tid & 63;
    const int w    = tid >> 6;

    const int raw = blockIdx.x;
    const int bid = (raw & 7) * 64 + (raw >> 3);     // XCD-contiguous chunks
    const int b   = bid >> 4;
    const int n0  = (bid & 15) * 64;

    const int lcol = lane & 15, q = lane >> 4;
    const int row  = n0 + w * 16 + lcol;             // this lane's adj/out row

    // A: adj[b][row][k], k = kc*32 + q*8  (32B-aligned, 8 fp32 per step)
    const float* aP = adj + ((size_t)b * NN + row) * NN + q * 8;
    // B: Yt[b][o][k], o = ni*16 + lcol    (16B-aligned bf16x8 per step)
    const unsigned short* bP[8];
    #pragma unroll
    for (int ni = 0; ni < 8; ++ni)
        bP[ni] = Yt + ((size_t)b * FOUT + ni * 16 + lcol) * NN + q * 8;

    f32x4 acc[8] = {};
    float rsum = 0.f;

    #pragma unroll 2
    for (int kc = 0; kc < 32; ++kc) {
        const float4 a0 = *(const float4*)(aP);
        const float4 a1 = *(const float4*)(aP + 4);
        aP += 32;
        rsum += ((a0.x + a0.y) + (a0.z + a0.w)) + ((a1.x + a1.y) + (a1.z + a1.w));
        uint4 pk;
        pk.x = pack2(a0.x, a0.y); pk.y = pack2(a0.z, a0.w);
        pk.z = pack2(a1.x, a1.y); pk.w = pack2(a1.z, a1.w);
        const bf16x8 a = *(const bf16x8*)&pk;
        #pragma unroll
        for (int ni = 0; ni < 8; ++ni) {
            const bf16x8 bb = *(const bf16x8*)bP[ni];
            bP[ni] += 32;
            acc[ni] = __builtin_amdgcn_mfma_f32_16x16x32_bf16(a, bb, acc[ni], 0, 0, 0);
        }
    }

    // full row sums: lanes sharing lcol hold disjoint k-quarters of row lcol
    rsum += __shfl_xor(rsum, 16);
    rsum += __shfl_xor(rsum, 32);

    // D layout: col = lane&15 (o), row = q*4 + r (within the 16-row tile).
    // Need 1/rowsum for rows q*4+r -> lane q*4+r (lcol = that row, q=0) has it.
    const int rq = q * 4;
    float sc[4];
    #pragma unroll
    for (int r = 0; r < 4; ++r) sc[r] = 1.0f / __shfl(rsum, rq + r);

    float* outB = out + ((size_t)(b * NN + n0 + w * 16)) * FOUT;
    #pragma unroll
    for (int ni = 0; ni < 8; ++ni) {
        const float bc = bias[ni * 16 + lcol];
        #pragma unroll
        for (int r = 0; r < 4; ++r) {
            float v = acc[ni][r] * sc[r] + bc;
            v = (v >= 0.f) ? v : 0.01f * v;
            outB[(size_t)(rq + r) * FOUT + ni * 16 + lcol] = v;  // 4x64B segments/instr
        }
    }
}

extern "C" void kernel_launch(void* const* d_in, const int* in_sizes, int n_in,
                              void* d_out, int out_size, void* d_ws, size_t ws_size,
                              hipStream_t stream) {
    const float* node = (const float*)d_in[0];   // [32,1024,128]
    const float* adj  = (const float*)d_in[1];   // [32,1024,1024]
    const float* W    = (const float*)d_in[2];   // [128,128]
    const float* bias = (const float*)d_in[3];   // [128]
    float* out = (float*)d_out;                  // [32,1024,128] fp32
    unsigned short* Yt = (unsigned short*)d_ws;  // [32,128,1024] bf16 = 8 MiB

    hipLaunchKernelGGL(y_kernel,   dim3(512), dim3(256), 0, stream, node, W, Yt);
    hipLaunchKernelGGL(gcn_kernel, dim3(512), dim3(256), 0, stream, adj, Yt, bias, out);
}